// Round 1
// baseline (1371.973 us; speedup 1.0000x reference)
//
#include <hip/hip_runtime.h>

#pragma clang fp contract(off)

#define T_STEPS 100
#define BATCH   2048
#define DIN     784
#define NH1     32
#define NH2     16
#define NOUT    10

// ---------------------------------------------------------------------------
// Kernel 1: layer-1 GEMM  cur1[row][c] = (x[row][:] . W1[c][:]) + b1[c]
// row = b*T + t  (x is [B][T][D] row-major).
// Numerics mimic OpenBLAS sgemm (what np.matmul uses): per output element a
// sequential-k FMA chain with KC=384 blocking; partial sums folded
// left-to-right ((p1+p2)+p3), bias added afterwards (separate rounding).
// 784 = 12*32 + 12*32 + 16  -> chunk boundaries align at sc==11 / sc==23.
// ---------------------------------------------------------------------------
__global__ __launch_bounds__(256) void snn_l1(const float* __restrict__ x,
                                              const float* __restrict__ W1,
                                              const float* __restrict__ b1,
                                              float* __restrict__ cur1) {
  __shared__ __align__(16) float wl[2][32 * 32];  // [buf][kk*32 + c]
  const int tid = threadIdx.x;
  const size_t row = (size_t)blockIdx.x * 256 + tid;
  const float4* __restrict__ xr = (const float4*)(x + row * DIN);
  const int sc_c = tid & 31;   // staged column
  const int sc_q = tid >> 5;   // float4 index within 32-k chunk (0..7)

  float acc[32], pacc[32];
#pragma unroll
  for (int c = 0; c < 32; ++c) { acc[c] = 0.0f; pacc[c] = 0.0f; }

  float4 xa[8], xb[8];
#pragma unroll
  for (int q = 0; q < 8; ++q) xa[q] = xr[q];

  // stage k-chunk 0 into wl[0] (transpose W1[c][k] -> wl[kk*32+c])
  {
    const float4 w4 = *(const float4*)(W1 + sc_c * DIN + sc_q * 4);
    wl[0][(sc_q * 4 + 0) * 32 + sc_c] = w4.x;
    wl[0][(sc_q * 4 + 1) * 32 + sc_c] = w4.y;
    wl[0][(sc_q * 4 + 2) * 32 + sc_c] = w4.z;
    wl[0][(sc_q * 4 + 3) * 32 + sc_c] = w4.w;
  }
  __syncthreads();

  for (int sc = 0; sc < 24; ++sc) {
    const int buf = sc & 1;

    // prefetch next x chunk (tail chunk has only 4 float4s)
    if (sc < 23) {
#pragma unroll
      for (int q = 0; q < 8; ++q) xb[q] = xr[(sc + 1) * 8 + q];
    } else {
#pragma unroll
      for (int q = 0; q < 4; ++q) xb[q] = xr[192 + q];
    }

    // stage next w chunk into wl[buf^1]
    if (sc < 23) {
      const float4 w4 = *(const float4*)(W1 + sc_c * DIN + (sc + 1) * 32 + sc_q * 4);
      wl[buf ^ 1][(sc_q * 4 + 0) * 32 + sc_c] = w4.x;
      wl[buf ^ 1][(sc_q * 4 + 1) * 32 + sc_c] = w4.y;
      wl[buf ^ 1][(sc_q * 4 + 2) * 32 + sc_c] = w4.z;
      wl[buf ^ 1][(sc_q * 4 + 3) * 32 + sc_c] = w4.w;
    } else if (sc_q < 4) {  // tail: k 768..783
      const float4 w4 = *(const float4*)(W1 + sc_c * DIN + 768 + sc_q * 4);
      wl[buf ^ 1][(sc_q * 4 + 0) * 32 + sc_c] = w4.x;
      wl[buf ^ 1][(sc_q * 4 + 1) * 32 + sc_c] = w4.y;
      wl[buf ^ 1][(sc_q * 4 + 2) * 32 + sc_c] = w4.z;
      wl[buf ^ 1][(sc_q * 4 + 3) * 32 + sc_c] = w4.w;
    }

    // compute current chunk: 32 k-steps x 32 cols, strictly k-ascending FMA
#pragma unroll
    for (int q = 0; q < 8; ++q) {
      const float xs[4] = {xa[q].x, xa[q].y, xa[q].z, xa[q].w};
#pragma unroll
      for (int j = 0; j < 4; ++j) {
        const float xv = xs[j];
        const int kk = q * 4 + j;
#pragma unroll
        for (int c4 = 0; c4 < 8; ++c4) {
          const float4 w4 = *(const float4*)&wl[buf][kk * 32 + c4 * 4];
          acc[c4 * 4 + 0] = __fmaf_rn(xv, w4.x, acc[c4 * 4 + 0]);
          acc[c4 * 4 + 1] = __fmaf_rn(xv, w4.y, acc[c4 * 4 + 1]);
          acc[c4 * 4 + 2] = __fmaf_rn(xv, w4.z, acc[c4 * 4 + 2]);
          acc[c4 * 4 + 3] = __fmaf_rn(xv, w4.w, acc[c4 * 4 + 3]);
        }
      }
    }

    // KC=384 block boundaries (after k=383 i.e. sc==11, and k=767 i.e. sc==23)
    if (sc == 11) {
#pragma unroll
      for (int c = 0; c < 32; ++c) { pacc[c] = acc[c]; acc[c] = 0.0f; }
    } else if (sc == 23) {
#pragma unroll
      for (int c = 0; c < 32; ++c) { pacc[c] = __fadd_rn(pacc[c], acc[c]); acc[c] = 0.0f; }
    }

    __syncthreads();
#pragma unroll
    for (int q = 0; q < 8; ++q) xa[q] = xb[q];
  }

  // tail compute: k 768..783 from wl[0]
#pragma unroll
  for (int q = 0; q < 4; ++q) {
    const float xs[4] = {xa[q].x, xa[q].y, xa[q].z, xa[q].w};
#pragma unroll
    for (int j = 0; j < 4; ++j) {
      const float xv = xs[j];
      const int kk = q * 4 + j;
#pragma unroll
      for (int c4 = 0; c4 < 8; ++c4) {
        const float4 w4 = *(const float4*)&wl[0][kk * 32 + c4 * 4];
        acc[c4 * 4 + 0] = __fmaf_rn(xv, w4.x, acc[c4 * 4 + 0]);
        acc[c4 * 4 + 1] = __fmaf_rn(xv, w4.y, acc[c4 * 4 + 1]);
        acc[c4 * 4 + 2] = __fmaf_rn(xv, w4.z, acc[c4 * 4 + 2]);
        acc[c4 * 4 + 3] = __fmaf_rn(xv, w4.w, acc[c4 * 4 + 3]);
      }
    }
  }

  // fold partials ((p1+p2)+p3), add bias, store
  const float4* __restrict__ b14 = (const float4*)b1;
  float4* __restrict__ o4 = (float4*)(cur1 + row * 32);
#pragma unroll
  for (int c4 = 0; c4 < 8; ++c4) {
    const float4 bb = b14[c4];
    float4 o;
    o.x = __fadd_rn(__fadd_rn(pacc[c4 * 4 + 0], acc[c4 * 4 + 0]), bb.x);
    o.y = __fadd_rn(__fadd_rn(pacc[c4 * 4 + 1], acc[c4 * 4 + 1]), bb.y);
    o.z = __fadd_rn(__fadd_rn(pacc[c4 * 4 + 2], acc[c4 * 4 + 2]), bb.z);
    o.w = __fadd_rn(__fadd_rn(pacc[c4 * 4 + 3], acc[c4 * 4 + 3]), bb.w);
    o4[c4] = o;
  }
}

// ---------------------------------------------------------------------------
// Kernel 2: LIF recurrence over T. One wave per sample; lane = neuron index
// for each layer (32 / 16 / 10). Spikes exchanged as __ballot bitmasks.
// Conditional add (mask ? w : 0) is bitwise-identical to np's fma(s,w,acc)
// since s in {0,1} and acc never holds -0.
// ---------------------------------------------------------------------------
__global__ __launch_bounds__(256) void snn_rec(const float* __restrict__ cur1,
                                               const float* __restrict__ W2,
                                               const float* __restrict__ b2,
                                               const float* __restrict__ W3,
                                               const float* __restrict__ b3,
                                               float* __restrict__ out) {
  const int lane = threadIdx.x & 63;
  const int s = blockIdx.x * 4 + (threadIdx.x >> 6);

  const int j2 = (lane < NH2) ? lane : 0;
  float w2r[NH1];
#pragma unroll
  for (int i = 0; i < NH1; ++i) w2r[i] = W2[j2 * NH1 + i];
  const float bias2 = b2[j2];

  const int j3 = (lane < NOUT) ? lane : 0;
  float w3r[NH2];
#pragma unroll
  for (int i = 0; i < NH2; ++i) w3r[i] = W3[j3 * NH2 + i];
  const float bias3 = b3[j3];

  float m1 = 0.0f, m2 = 0.0f, m3 = 0.0f;
  const float* __restrict__ c1p = cur1 + (size_t)s * (T_STEPS * NH1) + (lane & 31);

  float c1 = (lane < NH1) ? c1p[0] : 0.0f;

  for (int t = 0; t < T_STEPS; ++t) {
    float c1n = 0.0f;
    if (t < T_STEPS - 1 && lane < NH1) c1n = c1p[(t + 1) * NH1];

    // --- LIF layer 1 (thr 0.5) ---
    {
      const bool rst = m1 > 0.5f;
      const float mt = __fadd_rn(__fmul_rn(0.85f, m1), c1);
      m1 = rst ? 0.0f : mt;
    }
    const bool s1 = (m1 - 0.5f) > 0.0f;
    const unsigned int mk1 = (unsigned int)__ballot(s1);

    // --- layer 2: cur2 = s1 @ W2.T + b2 (sequential k=0..31) ---
    float a2 = 0.0f;
#pragma unroll
    for (int i = 0; i < NH1; ++i)
      a2 = __fadd_rn(a2, ((mk1 >> i) & 1u) ? w2r[i] : 0.0f);
    a2 = __fadd_rn(a2, bias2);

    {
      const bool rst = m2 > 0.5f;
      const float mt = __fadd_rn(__fmul_rn(0.85f, m2), a2);
      m2 = rst ? 0.0f : mt;
    }
    const bool s2 = ((m2 - 0.5f) > 0.0f) && (lane < NH2);
    const unsigned int mk2 = (unsigned int)__ballot(s2);

    // --- layer 3: cur3 = s2 @ W3.T + b3 (sequential k=0..15) ---
    float a3 = 0.0f;
#pragma unroll
    for (int i = 0; i < NH2; ++i)
      a3 = __fadd_rn(a3, ((mk2 >> i) & 1u) ? w3r[i] : 0.0f);
    a3 = __fadd_rn(a3, bias3);

    {
      const bool rst = m3 > 0.4f;
      const float mt = __fadd_rn(__fmul_rn(0.85f, m3), a3);
      m3 = rst ? 0.0f : mt;
    }
    const bool s3 = (m3 - 0.4f) > 0.0f;

    if (lane < NOUT)
      out[(size_t)t * (BATCH * NOUT) + (size_t)s * NOUT + lane] = s3 ? 1.0f : 0.0f;

    c1 = c1n;
  }
}

// ---------------------------------------------------------------------------
extern "C" void kernel_launch(void* const* d_in, const int* in_sizes, int n_in,
                              void* d_out, int out_size, void* d_ws, size_t ws_size,
                              hipStream_t stream) {
  (void)in_sizes; (void)n_in; (void)out_size; (void)ws_size;
  const float* x  = (const float*)d_in[0];
  const float* W1 = (const float*)d_in[1];
  const float* b1 = (const float*)d_in[2];
  const float* W2 = (const float*)d_in[3];
  const float* b2 = (const float*)d_in[4];
  const float* W3 = (const float*)d_in[5];
  const float* b3 = (const float*)d_in[6];
  float* out  = (float*)d_out;
  float* cur1 = (float*)d_ws;  // [B*T][32] = 26.2 MB scratch

  // Layer-1 GEMM over all (b,t) rows: 204800 rows / 256 per block = 800 blocks
  snn_l1<<<dim3(800), dim3(256), 0, stream>>>(x, W1, b1, cur1);
  // Recurrence: 2048 samples, 1 wave each, 4 waves per block = 512 blocks
  snn_rec<<<dim3(512), dim3(256), 0, stream>>>(cur1, W2, b2, W3, b3, out);
}

// Round 2
// 1299.003 us; speedup vs baseline: 1.0562x; 1.0562x over previous
//
#include <hip/hip_runtime.h>

#pragma clang fp contract(off)

#define T_STEPS 100
#define BATCH   2048
#define DIN     784
#define NH1     32
#define NH2     16
#define NOUT    10
#define LDSTR   36   // LDS row stride in floats (32 data + 4 pad, 16B-aligned rows)

// ---------------------------------------------------------------------------
// Pre-pass: W1 [32][784] -> W1T [784][32] so per-k weight rows are contiguous
// (feeds wave-uniform scalar loads in snn_l1).
// ---------------------------------------------------------------------------
__global__ __launch_bounds__(256) void w1_transpose(const float* __restrict__ W1,
                                                    float* __restrict__ W1T) {
  const int idx = blockIdx.x * 256 + threadIdx.x;
  if (idx < DIN * NH1) {
    const int k = idx >> 5, c = idx & 31;
    W1T[idx] = W1[c * DIN + k];
  }
}

// ---------------------------------------------------------------------------
// Layer-1 GEMM: thread = one row (b*T+t); x staged via LDS (coalesced global
// loads, per-lane ds_read_b128); W1T read via wave-uniform scalar loads ->
// v_fmac acc, s_w, v_x. Sequential-k FMA chain with KC=384 fold boundaries
// ((p1+p2)+p3)+bias — bit-exact vs OpenBLAS sgemm (absmax 0 in R1).
// ---------------------------------------------------------------------------
__global__ __launch_bounds__(256) void snn_l1(const float* __restrict__ x,
                                              const float* __restrict__ W1T,
                                              const float* __restrict__ b1,
                                              float* __restrict__ cur1) {
  __shared__ __align__(16) float xs[256 * LDSTR];  // 36.9 KB -> 4 blocks/CU
  const int tid = threadIdx.x;
  const size_t row0 = (size_t)blockIdx.x * 256;
  const float4* __restrict__ x4 = (const float4*)x;  // [row][196]
  const int q  = tid & 7, r8 = tid >> 3;  // full-chunk staging (8 f4/thread)
  const int q4 = tid & 3, r4 = tid >> 2;  // tail-chunk staging (4 f4/thread)

  float acc[32], fold[32];
#pragma unroll
  for (int c = 0; c < 32; ++c) { acc[c] = 0.0f; fold[c] = 0.0f; }

  float4 pf[8];

  // stage chunk 0 (k 0..31)
#pragma unroll
  for (int p = 0; p < 8; ++p)
    pf[p] = x4[(row0 + r8 + p * 32) * 196 + q];
#pragma unroll
  for (int p = 0; p < 8; ++p)
    *(float4*)&xs[(r8 + p * 32) * LDSTR + q * 4] = pf[p];
  __syncthreads();
  // prefetch chunk 1
#pragma unroll
  for (int p = 0; p < 8; ++p)
    pf[p] = x4[(row0 + r8 + p * 32) * 196 + 8 + q];

  for (int ch = 0; ch < 24; ++ch) {
    // ---- compute chunk ch: k = ch*32 .. ch*32+31, strictly ascending ----
#pragma unroll
    for (int kq = 0; kq < 8; ++kq) {
      const float4 xq = *(const float4*)&xs[tid * LDSTR + kq * 4];
      const float xv4[4] = {xq.x, xq.y, xq.z, xq.w};
#pragma unroll
      for (int j = 0; j < 4; ++j) {
        const float xv = xv4[j];
        const float* __restrict__ wr = W1T + (ch * 32 + kq * 4 + j) * 32;
#pragma unroll
        for (int c = 0; c < 32; ++c)
          acc[c] = __fmaf_rn(xv, wr[c], acc[c]);
      }
    }

    // KC=384 fold boundaries (after k=383 / k=767)
    if (ch == 11) {
#pragma unroll
      for (int c = 0; c < 32; ++c) { fold[c] = acc[c]; acc[c] = 0.0f; }
    } else if (ch == 23) {
#pragma unroll
      for (int c = 0; c < 32; ++c) { fold[c] = __fadd_rn(fold[c], acc[c]); acc[c] = 0.0f; }
    }

    __syncthreads();

    // ---- write prefetched chunk ch+1 into LDS ----
    if (ch < 23) {
#pragma unroll
      for (int p = 0; p < 8; ++p)
        *(float4*)&xs[(r8 + p * 32) * LDSTR + q * 4] = pf[p];
    } else {  // chunk 24 = tail (k 768..783), 4 f4/thread pattern
#pragma unroll
      for (int p = 0; p < 4; ++p)
        *(float4*)&xs[(r4 + p * 64) * LDSTR + q4 * 4] = pf[p];
    }

    // ---- prefetch chunk ch+2 ----
    if (ch < 22) {
#pragma unroll
      for (int p = 0; p < 8; ++p)
        pf[p] = x4[(row0 + r8 + p * 32) * 196 + (ch + 2) * 8 + q];
    } else if (ch == 22) {  // tail chunk: rows r4+p*64, quads 192+q4
#pragma unroll
      for (int p = 0; p < 4; ++p)
        pf[p] = x4[(row0 + r4 + p * 64) * 196 + 192 + q4];
    }

    __syncthreads();
  }

  // ---- tail compute: k 768..783 ----
#pragma unroll
  for (int kq = 0; kq < 4; ++kq) {
    const float4 xq = *(const float4*)&xs[tid * LDSTR + kq * 4];
    const float xv4[4] = {xq.x, xq.y, xq.z, xq.w};
#pragma unroll
    for (int j = 0; j < 4; ++j) {
      const float xv = xv4[j];
      const float* __restrict__ wr = W1T + (768 + kq * 4 + j) * 32;
#pragma unroll
      for (int c = 0; c < 32; ++c)
        acc[c] = __fmaf_rn(xv, wr[c], acc[c]);
    }
  }

  // epilogue: ((p1+p2)+p3) + bias, store row
  float4* __restrict__ o4 = (float4*)(cur1 + (row0 + tid) * 32);
#pragma unroll
  for (int c4 = 0; c4 < 8; ++c4) {
    float4 o;
    o.x = __fadd_rn(__fadd_rn(fold[c4 * 4 + 0], acc[c4 * 4 + 0]), b1[c4 * 4 + 0]);
    o.y = __fadd_rn(__fadd_rn(fold[c4 * 4 + 1], acc[c4 * 4 + 1]), b1[c4 * 4 + 1]);
    o.z = __fadd_rn(__fadd_rn(fold[c4 * 4 + 2], acc[c4 * 4 + 2]), b1[c4 * 4 + 2]);
    o.w = __fadd_rn(__fadd_rn(fold[c4 * 4 + 3], acc[c4 * 4 + 3]), b1[c4 * 4 + 3]);
    o4[c4] = o;
  }
}

// ---------------------------------------------------------------------------
// Kernel 2: LIF recurrence over T. One wave per sample; lane = neuron index
// (32/16/10). Spikes exchanged via __ballot masks. Numerics identical to R1
// (absmax 0). Only change: cur1 prefetch deepened to 2 iterations.
// ---------------------------------------------------------------------------
__global__ __launch_bounds__(256) void snn_rec(const float* __restrict__ cur1,
                                               const float* __restrict__ W2,
                                               const float* __restrict__ b2,
                                               const float* __restrict__ W3,
                                               const float* __restrict__ b3,
                                               float* __restrict__ out) {
  const int lane = threadIdx.x & 63;
  const int s = blockIdx.x * 4 + (threadIdx.x >> 6);

  const int j2 = (lane < NH2) ? lane : 0;
  float w2r[NH1];
#pragma unroll
  for (int i = 0; i < NH1; ++i) w2r[i] = W2[j2 * NH1 + i];
  const float bias2 = b2[j2];

  const int j3 = (lane < NOUT) ? lane : 0;
  float w3r[NH2];
#pragma unroll
  for (int i = 0; i < NH2; ++i) w3r[i] = W3[j3 * NH2 + i];
  const float bias3 = b3[j3];

  float m1 = 0.0f, m2 = 0.0f, m3 = 0.0f;
  const float* __restrict__ c1p = cur1 + (size_t)s * (T_STEPS * NH1) + (lane & 31);

  float c1a = (lane < NH1) ? c1p[0] : 0.0f;
  float c1b = (lane < NH1) ? c1p[NH1] : 0.0f;

  for (int t = 0; t < T_STEPS; ++t) {
    float c1n = 0.0f;
    if (t < T_STEPS - 2 && lane < NH1) c1n = c1p[(t + 2) * NH1];

    // --- LIF layer 1 (thr 0.5) ---
    {
      const bool rst = m1 > 0.5f;
      const float mt = __fadd_rn(__fmul_rn(0.85f, m1), c1a);
      m1 = rst ? 0.0f : mt;
    }
    const bool s1 = (m1 - 0.5f) > 0.0f;
    const unsigned int mk1 = (unsigned int)__ballot(s1);

    // --- layer 2: cur2 = s1 @ W2.T + b2 (sequential k=0..31; +0 adds exact) ---
    float a2 = 0.0f;
#pragma unroll
    for (int i = 0; i < NH1; ++i)
      a2 = __fadd_rn(a2, ((mk1 >> i) & 1u) ? w2r[i] : 0.0f);
    a2 = __fadd_rn(a2, bias2);

    {
      const bool rst = m2 > 0.5f;
      const float mt = __fadd_rn(__fmul_rn(0.85f, m2), a2);
      m2 = rst ? 0.0f : mt;
    }
    const bool s2 = ((m2 - 0.5f) > 0.0f) && (lane < NH2);
    const unsigned int mk2 = (unsigned int)__ballot(s2);

    // --- layer 3: cur3 = s2 @ W3.T + b3 (sequential k=0..15) ---
    float a3 = 0.0f;
#pragma unroll
    for (int i = 0; i < NH2; ++i)
      a3 = __fadd_rn(a3, ((mk2 >> i) & 1u) ? w3r[i] : 0.0f);
    a3 = __fadd_rn(a3, bias3);

    {
      const bool rst = m3 > 0.4f;
      const float mt = __fadd_rn(__fmul_rn(0.85f, m3), a3);
      m3 = rst ? 0.0f : mt;
    }
    const bool s3 = (m3 - 0.4f) > 0.0f;

    if (lane < NOUT)
      out[(size_t)t * (BATCH * NOUT) + (size_t)s * NOUT + lane] = s3 ? 1.0f : 0.0f;

    c1a = c1b;
    c1b = c1n;
  }
}

// ---------------------------------------------------------------------------
extern "C" void kernel_launch(void* const* d_in, const int* in_sizes, int n_in,
                              void* d_out, int out_size, void* d_ws, size_t ws_size,
                              hipStream_t stream) {
  (void)in_sizes; (void)n_in; (void)out_size; (void)ws_size;
  const float* x  = (const float*)d_in[0];
  const float* W1 = (const float*)d_in[1];
  const float* b1 = (const float*)d_in[2];
  const float* W2 = (const float*)d_in[3];
  const float* b2 = (const float*)d_in[4];
  const float* W3 = (const float*)d_in[5];
  const float* b3 = (const float*)d_in[6];
  float* out  = (float*)d_out;

  float* cur1 = (float*)d_ws;                               // 26.2 MB
  float* W1T  = (float*)((char*)d_ws + (size_t)BATCH * T_STEPS * NH1 * 4);  // +100 KB

  w1_transpose<<<dim3(98), dim3(256), 0, stream>>>(W1, W1T);
  snn_l1<<<dim3(800), dim3(256), 0, stream>>>(x, W1T, b1, cur1);
  snn_rec<<<dim3(512), dim3(256), 0, stream>>>(cur1, W2, b2, W3, b3, out);
}